// Round 15
// baseline (164.798 us; speedup 1.0000x reference)
//
#include <hip/hip_runtime.h>
#include <hip/hip_bf16.h>

// DirectionalConv mode='down': out[b,co,d,h,w] =
//   sum_{ci,i,k} x[b,ci, d+i-2, h+i-2, w+k-2] * W[co,ci,i,0,k] + bias[co]
// x: (2,32,48,64,128) f32, W: (32,32,5,1,5), out: (2,32,48,68,128) f32.
//
// R15 = R8 core, w-split for occupancy: block = quad-diagonal x 64-wide w
// (NCOL 68, LDS 34.8 KB -> 4 blocks/CU, 32 waves/CU). wh INNERMOST in the
// XCD-chunked order (R10's wh-outermost broke L2 reuse). 8 waves =
// (mt, wt, qh): 2 outputs x 16co x 32w each, 5-frag A ping-pong, s=col&7
// conflict-floor swizzle on both staging writes and MFMA reads.

#define NB   2
#define CIN  32
#define COUT 32
#define DD   48
#define HH   64
#define WW   128
#define DOUT 48
#define HO   68
#define WO   128

#define RS   256            // ushorts per col = 32 16B-chunks (8 planes * 4 octs)
#define NCOL 68             // local col = w - wlo + 2 (64 w + 4 halo)

typedef __attribute__((ext_vector_type(8))) short bf16x8;
typedef __attribute__((ext_vector_type(4))) float f32x4;

__device__ __forceinline__ unsigned short f32_to_bf16(float v) {
    unsigned int u; __builtin_memcpy(&u, &v, 4);
    u += 0x7FFFu + ((u >> 16) & 1u);        // RNE
    return (unsigned short)(u >> 16);
}
// packed pair conversion -> v_cvt_pk_bf16_f32 (1 instr for 2 floats)
__device__ __forceinline__ unsigned int pk2(float a, float b) {
    float2 t; t.x = a; t.y = b;
    __hip_bfloat162 r = __float22bfloat162_rn(t);
    unsigned int u; __builtin_memcpy(&u, &r, 4);
    return u;
}

// Pre-pack weights into MFMA A-fragment order, kk-major:
// frag f = (kk*5 + c)*2 + mt ; lane l ; 8 bf16 = W[mt*16+(l&15)][ci=(l>>4)*8+j][i=c][kk]
__global__ void prep_weights_kernel(const float* __restrict__ wgt,
                                    unsigned int* __restrict__ ws) {
    int s = blockIdx.x * 256 + threadIdx.x;     // 50 frags * 64 lanes = 3200 slots
    if (s >= 3200) return;
    int f = s >> 6, l = s & 63;
    int mt = f & 1, kkc = f >> 1;
    int kk = kkc / 5, c = kkc - kk * 5;         // kk-major
    int co = mt * 16 + (l & 15);
    int cib = (l >> 4) * 8;
    unsigned int u[4];
#pragma unroll
    for (int jp = 0; jp < 4; ++jp) {
        float v0 = wgt[co * 800 + (cib + 2 * jp + 0) * 25 + c * 5 + kk];
        float v1 = wgt[co * 800 + (cib + 2 * jp + 1) * 25 + c * 5 + kk];
        u[jp] = (unsigned int)f32_to_bf16(v0) | ((unsigned int)f32_to_bf16(v1) << 16);
    }
    uint4 pack; pack.x = u[0]; pack.y = u[1]; pack.z = u[2]; pack.w = u[3];
    reinterpret_cast<uint4*>(ws)[s] = pack;
}

__global__ void __launch_bounds__(512, 8)
dconv_kernel(const float* __restrict__ x,
             const float* __restrict__ bias,
             const bf16x8* __restrict__ wsf,   // packed A fragments
             float* __restrict__ out) {
    __shared__ __align__(16) unsigned short xs[NCOL * RS];   // 34816 B

    const int tid  = threadIdx.x;
    const int lane = tid & 63;
    const int wv   = tid >> 6;          // 0..7
    const int lr   = lane & 15;
    const int lg   = lane >> 4;
    // MFMA wave role: (mt, wt, qh)
    const int mt   = wv & 1;            // co-half
    const int wt   = (wv >> 1) & 1;     // 32-wide local w-tile
    const int q0   = (wv >> 2) * 2;     // output pair base (0 or 2)

    // ---- XCD-chunked remap, wh INNERMOST: 3408 = 8 * 426 ----
    // e = quad*2 + wh; consecutive e on one XCD = both halves of a quad,
    // then the next quad on the same diagonal (L2 plane reuse preserved).
    int bid = blockIdx.x;
    int e   = (bid & 7) * 426 + (bid >> 3);
    int wh  = e & 1;
    int eq  = e >> 1;                   // 0..1703
    int b   = (eq >= 852) ? 1 : 0;
    int r0  = eq - b * 852;
    int dlt = r0 / 12;
    int qq  = r0 - dlt * 12;
    const int d0  = 4 * qq;
    const int h0  = (d0 + dlt) % 71 - 3;    // -3..67
    const int wlo = wh * 64;

    // ---- early issue: kk=0 A-fragments + bias (hide under staging) ----
    const bf16x8* wl = wsf + lane;          // frag f at wl[f*64]
    bf16x8 aA[5], aB[5];
#pragma unroll
    for (int c = 0; c < 5; ++c) aA[c] = wl[(c * 2 + mt) * 64];
    float bs[4];
#pragma unroll
    for (int rg = 0; rg < 4; ++rg) bs[rg] = bias[mt * 16 + lg * 4 + rg];

    // ---- stage 8 planes: col-per-lane; wave = (oct, plane-half) ----
    // wave wv: oct = wv&3, jh = wv>>2 stages planes jh*4..jh*4+3.
    // cols: lane (0..63) + tail cols 64..67 (lane<4). OOB w/d/h -> 0.
    {
        const int octS = wv & 3, jh = wv >> 2;
        const size_t plane = (size_t)DD * HH * WW;
#pragma unroll
        for (int cc = 0; cc < 2; ++cc) {
            if (cc == 1 && lane >= 4) break;
            const int col = (cc == 0) ? lane : 64 + lane;
            const int wg  = wlo + col - 2;          // global w
            const bool wok = (unsigned)wg < (unsigned)WW;
            const int ssw = col & 7;
            unsigned short* cbase = &xs[col * RS];
            const float* xoct = x + ((size_t)b * CIN + octS * 8) * plane + wg;
#pragma unroll
            for (int jj = 0; jj < 4; ++jj) {
                const int j  = jh * 4 + jj;
                const int dz = d0 + j - 2, hz = h0 + j - 2;
                float v[8];
#pragma unroll
                for (int k = 0; k < 8; ++k) v[k] = 0.f;
                if (wok && ((unsigned)dz < (unsigned)DD) &&
                    ((unsigned)hz < (unsigned)HH)) {
                    const float* p = xoct + ((size_t)dz * HH + hz) * WW;
#pragma unroll
                    for (int k = 0; k < 8; ++k) v[k] = p[(size_t)k * plane];
                }
                uint4 ch;
                ch.x = pk2(v[0], v[1]); ch.y = pk2(v[2], v[3]);
                ch.z = pk2(v[4], v[5]); ch.w = pk2(v[6], v[7]);
                *reinterpret_cast<uint4*>(cbase + (((j * 4 + octS) ^ ssw) * 8)) = ch;
            }
        }
    }
    __syncthreads();

    // ---- MFMA: wave = (mt, 32w at wt, outputs q0..q0+1) ----
    f32x4 acc[2][2] = {};   // [qi][nt]

#define PREFA(DST, KK1)                                                        \
    _Pragma("unroll") for (int c = 0; c < 5; ++c)                              \
        DST[c] = wl[(((KK1) * 5 + c) * 2 + mt) * 64];

    // phys chunk for plane j=q0+j0: (q0+j0)^sb = q0 + (j0^sb) (q0 even).
    // even j0 -> chunk q0+j0+sb, odd j0 -> chunk q0+j0-sb; two-pointer + imm.
#define STEPK(KK, ACU)                                                         \
    {                                                                          \
        __builtin_amdgcn_s_setprio(1);                                         \
        _Pragma("unroll") for (int nt = 0; nt < 2; ++nt) {                     \
            const int col = wt * 32 + nt * 16 + lr + (KK);      /* 0..67 */    \
            const int s   = col & 7;                                           \
            const int sb  = s >> 2;                                            \
            const int lg2 = lg ^ (s & 3);                                      \
            const unsigned short* pc = &xs[col * RS + lg2 * 8];                \
            const unsigned short* pE = pc + (q0 + sb) * 32;                    \
            const unsigned short* pO = pc + (q0 - sb) * 32;                    \
            _Pragma("unroll") for (int j0 = 0; j0 < 6; ++j0) {                 \
                const unsigned short* p = (j0 & 1) ? pO : pE;                  \
                bf16x8 bv = *reinterpret_cast<const bf16x8*>(p + j0 * 32);     \
                const int qlo = (j0 > 4) ? (j0 - 4) : 0;                       \
                const int qhi = (j0 < 1) ? j0 : 1;                             \
                _Pragma("unroll") for (int qi = qlo; qi <= qhi; ++qi) {        \
                    acc[qi][nt] = __builtin_amdgcn_mfma_f32_16x16x32_bf16(     \
                        ACU[j0 - qi], bv, acc[qi][nt], 0, 0, 0);               \
                }                                                              \
            }                                                                  \
        }                                                                      \
        __builtin_amdgcn_s_setprio(0);                                         \
    }

    PREFA(aB, 1) STEPK(0, aA)
    PREFA(aA, 2) STEPK(1, aB)
    PREFA(aB, 3) STEPK(2, aA)
    PREFA(aA, 4) STEPK(3, aB)
    STEPK(4, aA)
#undef PREFA
#undef STEPK

    // ---- epilogue: D col=lane&15 (w), row=(lane>>4)*4+reg (co) ----
#pragma unroll
    for (int qi = 0; qi < 2; ++qi) {
        const int q  = q0 + qi;
        const int hq = h0 + q;
        if (hq < 0 || hq >= HO) continue;
        const int dq = d0 + q;
#pragma unroll
        for (int nt = 0; nt < 2; ++nt) {
            const int w = wlo + wt * 32 + nt * 16 + lr;
#pragma unroll
            for (int rg = 0; rg < 4; ++rg) {
                int co = mt * 16 + lg * 4 + rg;
                out[((((size_t)b * COUT + co) * DOUT + dq) * HO + hq) * WO + w] =
                    acc[qi][nt][rg] + bs[rg];
            }
        }
    }
}

extern "C" void kernel_launch(void* const* d_in, const int* in_sizes, int n_in,
                              void* d_out, int out_size, void* d_ws, size_t ws_size,
                              hipStream_t stream) {
    const float* x    = (const float*)d_in[0];
    const float* wgt  = (const float*)d_in[1];
    const float* bias = (const float*)d_in[2];
    float* out = (float*)d_out;
    unsigned int* ws = (unsigned int*)d_ws;

    // pack weights into A-fragment layout (51200 B in d_ws)
    prep_weights_kernel<<<13, 256, 0, stream>>>(wgt, ws);

    dconv_kernel<<<3408, 512, 0, stream>>>(x, bias, (const bf16x8*)ws, out);
}

// Round 16
// 62.223 us; speedup vs baseline: 2.6485x; 2.6485x over previous
//
#include <hip/hip_runtime.h>
#include <hip/hip_bf16.h>

// DirectionalConv mode='down': out[b,co,d,h,w] =
//   sum_{ci,i,k} x[b,ci, d+i-2, h+i-2, w+k-2] * W[co,ci,i,0,k] + bias[co]
// x: (2,32,48,64,128) f32, W: (32,32,5,1,5), out: (2,32,48,68,128) f32.
//
// R16 = R8 (quad-diagonal blocks, col-per-lane staging, s=col&7 swizzle,
// mt-split waves, 5-frag A ping-pong) + depth-4 pipelined staging made
// register-cheap: readfirstlane'd SGPR base pointers per ci (k) so each
// in-flight plane needs ONE VGPR offset (not 8x64-bit addr pairs — the
// actual cause of the R13/R14 spills), branchless clamped loads.

#define NB   2
#define CIN  32
#define COUT 32
#define DD   48
#define HH   64
#define WW   128
#define DOUT 48
#define HO   68
#define WO   128

#define RS   256            // ushorts per col = 32 16B-chunks (8 planes * 4 octs)
#define NCOL 132            // col = w + 2; cols 0,1,130,131 always zero

typedef __attribute__((ext_vector_type(8))) short bf16x8;
typedef __attribute__((ext_vector_type(4))) float f32x4;

__device__ __forceinline__ unsigned short f32_to_bf16(float v) {
    unsigned int u; __builtin_memcpy(&u, &v, 4);
    u += 0x7FFFu + ((u >> 16) & 1u);        // RNE
    return (unsigned short)(u >> 16);
}
// packed pair conversion -> v_cvt_pk_bf16_f32 (1 instr for 2 floats)
__device__ __forceinline__ unsigned int pk2(float a, float b) {
    float2 t; t.x = a; t.y = b;
    __hip_bfloat162 r = __float22bfloat162_rn(t);
    unsigned int u; __builtin_memcpy(&u, &r, 4);
    return u;
}

// Pre-pack weights into MFMA A-fragment order, kk-major:
// frag f = (kk*5 + c)*2 + mt ; lane l ; 8 bf16 = W[mt*16+(l&15)][ci=(l>>4)*8+j][i=c][kk]
__global__ void prep_weights_kernel(const float* __restrict__ wgt,
                                    unsigned int* __restrict__ ws) {
    int s = blockIdx.x * 256 + threadIdx.x;     // 50 frags * 64 lanes = 3200 slots
    if (s >= 3200) return;
    int f = s >> 6, l = s & 63;
    int mt = f & 1, kkc = f >> 1;
    int kk = kkc / 5, c = kkc - kk * 5;         // kk-major
    int co = mt * 16 + (l & 15);
    int cib = (l >> 4) * 8;
    unsigned int u[4];
#pragma unroll
    for (int jp = 0; jp < 4; ++jp) {
        float v0 = wgt[co * 800 + (cib + 2 * jp + 0) * 25 + c * 5 + kk];
        float v1 = wgt[co * 800 + (cib + 2 * jp + 1) * 25 + c * 5 + kk];
        u[jp] = (unsigned int)f32_to_bf16(v0) | ((unsigned int)f32_to_bf16(v1) << 16);
    }
    uint4 pack; pack.x = u[0]; pack.y = u[1]; pack.z = u[2]; pack.w = u[3];
    reinterpret_cast<uint4*>(ws)[s] = pack;
}

__global__ void __launch_bounds__(512, 4)
dconv_kernel(const float* __restrict__ x,
             const float* __restrict__ bias,
             const bf16x8* __restrict__ wsf,   // packed A fragments
             float* __restrict__ out) {
    __shared__ __align__(16) unsigned short xs[NCOL * RS];   // 67584 B

    const int tid  = threadIdx.x;
    const int lane = tid & 63;
    const int wv   = tid >> 6;          // 0..7
    const int lr   = lane & 15;
    const int lg   = lane >> 4;
    const int mt   = wv & 1;            // co-half owned by this wave (MFMA phase)
    const int wbase = (wv >> 1) * 32;   // 32-wide w-tile (MFMA phase)

    // ---- quad-diagonal, XCD-chunked block remap (R8) ----
    int bid = blockIdx.x;
    int e   = (bid & 7) * 213 + (bid >> 3);
    int b   = (e >= 852) ? 1 : 0;
    int r0  = e - b * 852;
    int dlt = r0 / 12;
    int qq  = r0 - dlt * 12;
    const int d0 = 4 * qq;
    const int h0 = (d0 + dlt) % 71 - 3;     // -3..67

    // ---- early issue: kk=0 A-fragments + bias (hide under staging) ----
    const bf16x8* wl = wsf + lane;          // frag f at wl[f*64]
    bf16x8 aA[5], aB[5];
#pragma unroll
    for (int c = 0; c < 5; ++c) aA[c] = wl[(c * 2 + mt) * 64];
    float bs[4];
#pragma unroll
    for (int rg = 0; rg < 4; ++rg) bs[rg] = bias[mt * 16 + lg * 4 + rg];

    // ---- zero the 4 always-zero halo cols (0,1,130,131), all 32 chunks ----
    if (tid < 128) {
        int colIdx = tid >> 5;              // 0..3
        int ch     = tid & 31;              // 0..31
        int col    = (colIdx < 2) ? colIdx : 128 + colIdx;
        f32x4 z = {};
        *reinterpret_cast<f32x4*>(&xs[col * RS + ch * 8]) = z;
    }

    // ---- stage 8 diagonal planes: col-per-lane, depth-4 pipeline ----
    // SGPR-base addressing: oct/wh readfirstlane'd -> 8 uniform base
    // pointers xk[k]; per plane only ONE divergent 32-bit offset (w0s).
    {
        const int octu = __builtin_amdgcn_readfirstlane((tid >> 6) >> 1); // 0..3
        const int whu  = __builtin_amdgcn_readfirstlane((tid >> 6) & 1);  // 0..1
        const int w0s  = whu * 64 + lane;   // 0..127
        const int colS = w0s + 2;
        const int ssw  = colS & 7;
        unsigned short* cbase = &xs[colS * RS];
        const size_t plane = (size_t)DD * HH * WW;
        const float* xk[8];
#pragma unroll
        for (int k = 0; k < 8; ++k)
            xk[k] = x + ((size_t)b * CIN + octu * 8 + k) * plane;   // SGPR pairs

        float va[8], vb[8], vc[8], vd[8];

#define LOADJ(V, J)                                                            \
        {                                                                      \
            const int dz  = d0 + (J) - 2, hz = h0 + (J) - 2;                   \
            const int dzc = dz < 0 ? 0 : (dz > DD - 1 ? DD - 1 : dz);          \
            const int hzc = hz < 0 ? 0 : (hz > HH - 1 ? HH - 1 : hz);          \
            const bool ok = (dz == dzc) & (hz == hzc);      /* uniform */      \
            const int off = (dzc * HH + hzc) * WW + w0s;    /* 1 VGPR */       \
            _Pragma("unroll") for (int k = 0; k < 8; ++k)                      \
                V[k] = xk[k][off];                                             \
            _Pragma("unroll") for (int k = 0; k < 8; ++k)                      \
                V[k] = ok ? V[k] : 0.f;                                        \
        }
#define PACKJ(V, J)                                                            \
        {                                                                      \
            uint4 ch;                                                          \
            ch.x = pk2(V[0], V[1]); ch.y = pk2(V[2], V[3]);                    \
            ch.z = pk2(V[4], V[5]); ch.w = pk2(V[6], V[7]);                    \
            *reinterpret_cast<uint4*>(cbase +                                  \
                ((((J) * 4 + octu) ^ ssw) * 8)) = ch;                          \
        }

        LOADJ(va, 0) LOADJ(vb, 1) LOADJ(vc, 2) LOADJ(vd, 3)
        PACKJ(va, 0) LOADJ(va, 4)
        PACKJ(vb, 1) LOADJ(vb, 5)
        PACKJ(vc, 2) LOADJ(vc, 6)
        PACKJ(vd, 3) LOADJ(vd, 7)
        PACKJ(va, 4) PACKJ(vb, 5) PACKJ(vc, 6) PACKJ(vd, 7)

#undef LOADJ
#undef PACKJ
    }
    __syncthreads();

    // ---- MFMA: wave = (mt, 32w, 4q); full-kk ping-pong A prefetch ----
    f32x4 acc[4][2] = {};   // [q][nt]

#define PREFA(DST, KK1)                                                        \
    _Pragma("unroll") for (int c = 0; c < 5; ++c)                              \
        DST[c] = wl[(((KK1) * 5 + c) * 2 + mt) * 64];

    // phys chunk for (j, lg) at col: P = (j ^ sb)*4 + (lg ^ (s&3)), sb = s>>2.
    // two-pointer form: even j -> pE + j*32, odd j -> pO + j*32 (ushorts).
#define STEPK(KK, ACU)                                                         \
    {                                                                          \
        __builtin_amdgcn_s_setprio(1);                                         \
        _Pragma("unroll") for (int nt = 0; nt < 2; ++nt) {                     \
            const int col = wbase + nt * 16 + lr + (KK);                       \
            const int s   = col & 7;                                           \
            const int sb  = s >> 2;                                            \
            const int lg2 = lg ^ (s & 3);                                      \
            const unsigned short* pc = &xs[col * RS + lg2 * 8];                \
            const unsigned short* pE = pc + sb * 32;                           \
            const unsigned short* pO = pc - sb * 32;                           \
            _Pragma("unroll") for (int j = 0; j < 8; ++j) {                    \
                const unsigned short* p = (j & 1) ? pO : pE;                   \
                bf16x8 bv = *reinterpret_cast<const bf16x8*>(p + j * 32);      \
                const int qlo = (j > 4) ? (j - 4) : 0;                         \
                const int qhi = (j < 3) ? j : 3;                               \
                _Pragma("unroll") for (int q = qlo; q <= qhi; ++q) {           \
                    acc[q][nt] = __builtin_amdgcn_mfma_f32_16x16x32_bf16(      \
                        ACU[j - q], bv, acc[q][nt], 0, 0, 0);                  \
                }                                                              \
            }                                                                  \
        }                                                                      \
        __builtin_amdgcn_s_setprio(0);                                         \
    }

    PREFA(aB, 1) STEPK(0, aA)
    PREFA(aA, 2) STEPK(1, aB)
    PREFA(aB, 3) STEPK(2, aA)
    PREFA(aA, 4) STEPK(3, aB)
    STEPK(4, aA)
#undef PREFA
#undef STEPK

    // ---- epilogue: D col=lane&15 (w), row=(lane>>4)*4+reg (co) ----
#pragma unroll
    for (int q = 0; q < 4; ++q) {
        const int hq = h0 + q;
        if (hq < 0 || hq >= HO) continue;
        const int dq = d0 + q;
#pragma unroll
        for (int nt = 0; nt < 2; ++nt) {
            const int w = wbase + nt * 16 + lr;
#pragma unroll
            for (int rg = 0; rg < 4; ++rg) {
                int co = mt * 16 + lg * 4 + rg;
                out[((((size_t)b * COUT + co) * DOUT + dq) * HO + hq) * WO + w] =
                    acc[q][nt][rg] + bs[rg];
            }
        }
    }
}

extern "C" void kernel_launch(void* const* d_in, const int* in_sizes, int n_in,
                              void* d_out, int out_size, void* d_ws, size_t ws_size,
                              hipStream_t stream) {
    const float* x    = (const float*)d_in[0];
    const float* wgt  = (const float*)d_in[1];
    const float* bias = (const float*)d_in[2];
    float* out = (float*)d_out;
    unsigned int* ws = (unsigned int*)d_ws;

    // pack weights into A-fragment layout (51200 B in d_ws)
    prep_weights_kernel<<<13, 256, 0, stream>>>(wgt, ws);

    dconv_kernel<<<1704, 512, 0, stream>>>(x, bias, (const bf16x8*)ws, out);
}